// Round 8
// baseline (109.963 us; speedup 1.0000x reference)
//
#include <hip/hip_runtime.h>

#define HDIM    256
#define KH      128    // K-half per ks-group
#define HHALF   128
#define NTYPE   100
#define RPB     8      // crystals (rows) per block
#define S       260    // LDS row stride in floats (256 + 4 pad)
#define THREADS 512

typedef float f32x4_n __attribute__((ext_vector_type(4)));  // native vec for nontemporal

__device__ __forceinline__ float silu_f(float x) {
    return x / (1.0f + __expf(-x));
}

#define LD4(p) (*(const float4*)(p))
#define FMA4(A, s, v) do { (A).x += (s)*(v).x; (A).y += (s)*(v).y; \
                           (A).z += (s)*(v).z; (A).w += (s)*(v).w; } while (0)

// 2 rows x 4 cols per thread over K k-rows (K=128: one ks-half), register
// ping-pong weight prefetch (8 rows in flight). h reads are LDS broadcasts.
// Accumulates only; caller does cross-ks reduce + bias + act + store.
template<int K>
__device__ __forceinline__ void gemm_acc_2x4(
    const float* hrow0, const float* hrow1,
    const float* __restrict__ W, const int ldw, const int j0,
    float4& acc0, float4& acc1)
{
    const float* wp = W + j0;

    float4 x0 = LD4(wp);           float4 x1 = LD4(wp + ldw);
    float4 x2 = LD4(wp + 2 * ldw); float4 x3 = LD4(wp + 3 * ldw);
    float4 x4 = LD4(wp + 4 * ldw); float4 x5 = LD4(wp + 5 * ldw);
    float4 x6 = LD4(wp + 6 * ldw); float4 x7 = LD4(wp + 7 * ldw);

#define C8(b0,b1,b2,b3,b4,b5,b6,b7,kk) do { \
    float4 ha = LD4(hrow0 + (kk)); float4 hb = LD4(hrow0 + (kk) + 4); \
    float4 ga = LD4(hrow1 + (kk)); float4 gb = LD4(hrow1 + (kk) + 4); \
    FMA4(acc0, ha.x, b0); FMA4(acc1, ga.x, b0); \
    FMA4(acc0, ha.y, b1); FMA4(acc1, ga.y, b1); \
    FMA4(acc0, ha.z, b2); FMA4(acc1, ga.z, b2); \
    FMA4(acc0, ha.w, b3); FMA4(acc1, ga.w, b3); \
    FMA4(acc0, hb.x, b4); FMA4(acc1, gb.x, b4); \
    FMA4(acc0, hb.y, b5); FMA4(acc1, gb.y, b5); \
    FMA4(acc0, hb.z, b6); FMA4(acc1, gb.z, b6); \
    FMA4(acc0, hb.w, b7); FMA4(acc1, gb.w, b7); } while (0)

#pragma unroll 1
    for (int k = 0; k <= K - 32; k += 16) {
        const float* wy = wp + (size_t)(k + 8) * ldw;
        float4 y0 = LD4(wy);           float4 y1 = LD4(wy + ldw);
        float4 y2 = LD4(wy + 2 * ldw); float4 y3 = LD4(wy + 3 * ldw);
        float4 y4 = LD4(wy + 4 * ldw); float4 y5 = LD4(wy + 5 * ldw);
        float4 y6 = LD4(wy + 6 * ldw); float4 y7 = LD4(wy + 7 * ldw);
        C8(x0, x1, x2, x3, x4, x5, x6, x7, k);
        const float* wx = wp + (size_t)(k + 16) * ldw;
        x0 = LD4(wx);           x1 = LD4(wx + ldw);
        x2 = LD4(wx + 2 * ldw); x3 = LD4(wx + 3 * ldw);
        x4 = LD4(wx + 4 * ldw); x5 = LD4(wx + 5 * ldw);
        x6 = LD4(wx + 6 * ldw); x7 = LD4(wx + 7 * ldw);
        C8(y0, y1, y2, y3, y4, y5, y6, y7, k + 8);
    }
    {   // epilogue: rows K-16..K-1 (x already holds K-16..K-9)
        const float* wy = wp + (size_t)(K - 8) * ldw;
        float4 y0 = LD4(wy);           float4 y1 = LD4(wy + ldw);
        float4 y2 = LD4(wy + 2 * ldw); float4 y3 = LD4(wy + 3 * ldw);
        float4 y4 = LD4(wy + 4 * ldw); float4 y5 = LD4(wy + 5 * ldw);
        float4 y6 = LD4(wy + 6 * ldw); float4 y7 = LD4(wy + 7 * ldw);
        C8(x0, x1, x2, x3, x4, x5, x6, x7, K - 16);
        C8(y0, y1, y2, y3, y4, y5, y6, y7, K - 8);
    }
#undef C8
}

// One block = 8 crystals, 512 threads, K split in halves across tid bit 6
// (main) / bit 5 (heads, logits). Partials reduced via stride-9 LDS (bank-
// conflict-free: 9 coprime 32).
__global__ __launch_bounds__(THREADS, 4) void crystal_kernel(
    const int* __restrict__ batch, int N,
    const float* __restrict__ t_emb,
    const float* __restrict__ w1a, const float* __restrict__ b1a,
    const float* __restrict__ w2a, const float* __restrict__ b2a,
    const float* __restrict__ wc1, const float* __restrict__ bc1,
    const float* __restrict__ wc2, const float* __restrict__ bc2,
    const float* __restrict__ wl1, const float* __restrict__ bl1,
    const float* __restrict__ wl2, const float* __restrict__ bl2,
    const float* __restrict__ wt,  const float* __restrict__ bt,
    float* __restrict__ coord_b,   // [B,3]  ws
    float* __restrict__ logits_b,  // [B,100] ws
    float* __restrict__ cell_out)  // d_out + N*3, [B,6]
{
    __shared__ float bufA[RPB * S];   // h0, then h
    __shared__ float bufB[RPB * S];   // h1, then gc(0..127)/gl(128..255)
    __shared__ float red[256 * 9];    // cross-ks partial sums
    __shared__ int   lb_s[RPB + 1];
    __shared__ float cnt_s[RPB];

    const int tid = threadIdx.x;
    const int R0  = blockIdx.x * RPB;

    // atom ranges via binary search on sorted batch
    if (tid <= RPB) {
        int v = R0 + tid;
        int lo = 0, hi = N;
        while (lo < hi) { int mid = (lo + hi) >> 1; if (batch[mid] < v) lo = mid + 1; else hi = mid; }
        lb_s[tid] = lo;
    }

    // stage t_emb rows R0..R0+7 (each thread exactly one float4, coalesced)
    {
        const float4* src = (const float4*)(t_emb + (size_t)R0 * HDIM);
        int r = tid >> 6, kq = tid & 63;
        *(float4*)&bufA[r * S + kq * 4] = src[r * 64 + kq];
    }
    __syncthreads();
    if (tid < RPB) cnt_s[tid] = (float)(lb_s[tid + 1] - lb_s[tid]);

    const int cg = tid & 63;          // 64 col-groups x 4 cols = 256
    const int ks = (tid >> 6) & 1;    // K-half
    const int rg = tid >> 7;          // 4 row-groups x 2 rows = 8
    const int j0 = cg * 4;
    const int r0 = rg * 2;
    const int slot = cg + 64 * rg;    // 0..255

#define RED_WR(sl, a0, a1) do { float* rp = &red[(sl) * 9]; \
    rp[0]=(a0).x; rp[1]=(a0).y; rp[2]=(a0).z; rp[3]=(a0).w; \
    rp[4]=(a1).x; rp[5]=(a1).y; rp[6]=(a1).z; rp[7]=(a1).w; } while (0)
#define RED_ADD(sl, a0, a1) do { const float* rp = &red[(sl) * 9]; \
    (a0).x+=rp[0]; (a0).y+=rp[1]; (a0).z+=rp[2]; (a0).w+=rp[3]; \
    (a1).x+=rp[4]; (a1).y+=rp[5]; (a1).z+=rp[6]; (a1).w+=rp[7]; } while (0)

    // ---------------- layer 1: h1 = silu(h0 @ w1a + b1a)   bufA -> bufB
    {
        float4 a0 = make_float4(0.f,0.f,0.f,0.f), a1 = a0;
        gemm_acc_2x4<KH>(&bufA[r0 * S + ks * KH], &bufA[(r0 + 1) * S + ks * KH],
                         w1a + (size_t)ks * KH * HDIM, HDIM, j0, a0, a1);
        if (ks) RED_WR(slot, a0, a1);
        __syncthreads();
        if (!ks) {
            RED_ADD(slot, a0, a1);
            float4 b4 = LD4(b1a + j0);
            float4 r0v, r1v;
            r0v.x = silu_f(a0.x + b4.x); r0v.y = silu_f(a0.y + b4.y);
            r0v.z = silu_f(a0.z + b4.z); r0v.w = silu_f(a0.w + b4.w);
            r1v.x = silu_f(a1.x + b4.x); r1v.y = silu_f(a1.y + b4.y);
            r1v.z = silu_f(a1.z + b4.z); r1v.w = silu_f(a1.w + b4.w);
            *(float4*)&bufB[r0 * S + j0] = r0v;
            *(float4*)&bufB[(r0 + 1) * S + j0] = r1v;
        }
        __syncthreads();
    }

    // ---------------- layer 2: h = h1 @ w2a + b2a          bufB -> bufA
    {
        float4 a0 = make_float4(0.f,0.f,0.f,0.f), a1 = a0;
        gemm_acc_2x4<KH>(&bufB[r0 * S + ks * KH], &bufB[(r0 + 1) * S + ks * KH],
                         w2a + (size_t)ks * KH * HDIM, HDIM, j0, a0, a1);
        if (ks) RED_WR(slot, a0, a1);
        __syncthreads();
        if (!ks) {
            RED_ADD(slot, a0, a1);
            float4 b4 = LD4(b2a + j0);
            float4 r0v, r1v;
            r0v.x = a0.x + b4.x; r0v.y = a0.y + b4.y;
            r0v.z = a0.z + b4.z; r0v.w = a0.w + b4.w;
            r1v.x = a1.x + b4.x; r1v.y = a1.y + b4.y;
            r1v.z = a1.z + b4.z; r1v.w = a1.w + b4.w;
            *(float4*)&bufA[r0 * S + j0] = r0v;
            *(float4*)&bufA[(r0 + 1) * S + j0] = r1v;
        }
        __syncthreads();
    }

    // ---------------- heads: coord (tid<256) / cell (tid>=256)  bufA -> bufB
    {
        const int  t    = tid & 255;
        const bool ic   = (tid >= 256);
        const int  hcg  = t & 31;        // 32 col-groups x 4 = 128 cols
        const int  hks  = (t >> 5) & 1;  // K-half
        const int  hrg  = t >> 6;        // 4 row-groups x 2 rows = 8
        const int  hj0  = hcg * 4;
        const int  hr0  = hrg * 2;
        const int  hslot = hcg + 32 * hrg + (ic ? 128 : 0);
        const float* W  = ic ? wl1 : wc1;
        const float* bb = ic ? bl1 : bc1;

        float4 a0 = make_float4(0.f,0.f,0.f,0.f), a1 = a0;
        gemm_acc_2x4<KH>(&bufA[hr0 * S + hks * KH], &bufA[(hr0 + 1) * S + hks * KH],
                         W + (size_t)hks * KH * HHALF, HHALF, hj0, a0, a1);
        if (hks) RED_WR(hslot, a0, a1);
        __syncthreads();
        if (!hks) {
            RED_ADD(hslot, a0, a1);
            // segment_sum == count * h; scale commutes through the dot product
            const float sA = ic ? cnt_s[hr0]     : 1.f;
            const float sB = ic ? cnt_s[hr0 + 1] : 1.f;
            float4 b4 = LD4(bb + hj0);
            float4 r0v, r1v;
            r0v.x = silu_f(a0.x * sA + b4.x); r0v.y = silu_f(a0.y * sA + b4.y);
            r0v.z = silu_f(a0.z * sA + b4.z); r0v.w = silu_f(a0.w * sA + b4.w);
            r1v.x = silu_f(a1.x * sB + b4.x); r1v.y = silu_f(a1.y * sB + b4.y);
            r1v.z = silu_f(a1.z * sB + b4.z); r1v.w = silu_f(a1.w * sB + b4.w);
            const int off = ic ? HHALF : 0;
            *(float4*)&bufB[hr0 * S + off + hj0] = r0v;
            *(float4*)&bufB[(hr0 + 1) * S + off + hj0] = r1v;
        }
        __syncthreads();
    }

    // ---------------- logits (lcg<25) + tiny heads (lcg>=25)
    {
        const int lcg = tid & 31;
        const int lks = (tid >> 5) & 1;
        const int lrg = tid >> 6;        // row 0..7
        float4 lacc = make_float4(0.f,0.f,0.f,0.f);

        if (lcg < 25) {
            const int lj0 = lcg * 4;
            const float* hr = &bufA[lrg * S + lks * KH];
            const float* wp = wt + (size_t)lks * KH * NTYPE + lj0;

            float4 x0 = LD4(wp);             float4 x1 = LD4(wp + NTYPE);
            float4 x2 = LD4(wp + 2 * NTYPE); float4 x3 = LD4(wp + 3 * NTYPE);
            float4 x4 = LD4(wp + 4 * NTYPE); float4 x5 = LD4(wp + 5 * NTYPE);
            float4 x6 = LD4(wp + 6 * NTYPE); float4 x7 = LD4(wp + 7 * NTYPE);

#define C8L(b0,b1,b2,b3,b4,b5,b6,b7,kk) do { \
    float4 ha = LD4(hr + (kk)); float4 hb = LD4(hr + (kk) + 4); \
    FMA4(lacc, ha.x, b0); FMA4(lacc, ha.y, b1); \
    FMA4(lacc, ha.z, b2); FMA4(lacc, ha.w, b3); \
    FMA4(lacc, hb.x, b4); FMA4(lacc, hb.y, b5); \
    FMA4(lacc, hb.z, b6); FMA4(lacc, hb.w, b7); } while (0)

#pragma unroll 1
            for (int k = 0; k <= KH - 32; k += 16) {
                const float* wy = wp + (size_t)(k + 8) * NTYPE;
                float4 y0 = LD4(wy);             float4 y1 = LD4(wy + NTYPE);
                float4 y2 = LD4(wy + 2 * NTYPE); float4 y3 = LD4(wy + 3 * NTYPE);
                float4 y4 = LD4(wy + 4 * NTYPE); float4 y5 = LD4(wy + 5 * NTYPE);
                float4 y6 = LD4(wy + 6 * NTYPE); float4 y7 = LD4(wy + 7 * NTYPE);
                C8L(x0, x1, x2, x3, x4, x5, x6, x7, k);
                const float* wx = wp + (size_t)(k + 16) * NTYPE;
                x0 = LD4(wx);             x1 = LD4(wx + NTYPE);
                x2 = LD4(wx + 2 * NTYPE); x3 = LD4(wx + 3 * NTYPE);
                x4 = LD4(wx + 4 * NTYPE); x5 = LD4(wx + 5 * NTYPE);
                x6 = LD4(wx + 6 * NTYPE); x7 = LD4(wx + 7 * NTYPE);
                C8L(y0, y1, y2, y3, y4, y5, y6, y7, k + 8);
            }
            {
                const float* wy = wp + (size_t)(KH - 8) * NTYPE;
                float4 y0 = LD4(wy);             float4 y1 = LD4(wy + NTYPE);
                float4 y2 = LD4(wy + 2 * NTYPE); float4 y3 = LD4(wy + 3 * NTYPE);
                float4 y4 = LD4(wy + 4 * NTYPE); float4 y5 = LD4(wy + 5 * NTYPE);
                float4 y6 = LD4(wy + 6 * NTYPE); float4 y7 = LD4(wy + 7 * NTYPE);
                C8L(x0, x1, x2, x3, x4, x5, x6, x7, KH - 16);
                C8L(y0, y1, y2, y3, y4, y5, y6, y7, KH - 8);
            }
#undef C8L
        } else {
            // 112 spare lanes cover 24 coord + 48 cell outputs (K=128 dots)
            const int idx = ((lrg << 1) | lks) * 7 + (lcg - 25);  // 0..111
            if (idx < 24) {
                int r = idx / 3, c = idx - 3 * r;
                float a = 0.f;
#pragma unroll 4
                for (int k = 0; k < HHALF; k += 4) {
                    float4 hv = LD4(&bufB[r * S + k]);
                    a += hv.x * wc2[(k + 0) * 3 + c] + hv.y * wc2[(k + 1) * 3 + c]
                       + hv.z * wc2[(k + 2) * 3 + c] + hv.w * wc2[(k + 3) * 3 + c];
                }
                coord_b[(size_t)(R0 + r) * 3 + c] = a + bc2[c];
            } else if (idx < 72) {
                int t2 = idx - 24;
                int r = t2 / 6, c = t2 - 6 * r;
                float a = 0.f;
#pragma unroll 4
                for (int k = 0; k < HHALF; k += 4) {
                    float4 hv = LD4(&bufB[r * S + HHALF + k]);
                    a += hv.x * wl2[(k + 0) * 6 + c] + hv.y * wl2[(k + 1) * 6 + c]
                       + hv.z * wl2[(k + 2) * 6 + c] + hv.w * wl2[(k + 3) * 6 + c];
                }
                cell_out[(size_t)(R0 + r) * 6 + c] = a + bl2[c];
            }
        }

        // cross-ks reduce for logits
        if (lcg < 25 && lks) {
            float* rp = &red[(lcg + 25 * lrg) * 5];
            rp[0] = lacc.x; rp[1] = lacc.y; rp[2] = lacc.z; rp[3] = lacc.w;
        }
        __syncthreads();
        if (lcg < 25 && !lks) {
            const float* rp = &red[(lcg + 25 * lrg) * 5];
            const int lj0 = lcg * 4;
            float4 b4 = LD4(bt + lj0);
            *(float4*)&logits_b[(size_t)(R0 + lrg) * NTYPE + lj0] =
                make_float4(lacc.x + rp[0] + b4.x, lacc.y + rp[1] + b4.y,
                            lacc.z + rp[2] + b4.z, lacc.w + rp[3] + b4.w);
        }
    }
#undef RED_WR
#undef RED_ADD
}

// Gather per-crystal tables out to per-atom outputs. Write-bound (~206 MB).
__global__ __launch_bounds__(256) void scatter_kernel(
    const int* __restrict__ batch,
    const float*  __restrict__ coord_b,
    const f32x4_n* __restrict__ logits_b4,  // [B][25] float4
    float*  __restrict__ out_coord,         // [N*3]
    f32x4_n* __restrict__ out_logits4,      // [N*25] float4
    int N)
{
    const int stride = gridDim.x * blockDim.x;
    const int g0 = blockIdx.x * blockDim.x + threadIdx.x;

    const int tot_c = N * 3;
    for (int g = g0; g < tot_c; g += stride) {
        unsigned ug = (unsigned)g;
        unsigned i = ug / 3u;
        unsigned c = ug - i * 3u;
        __builtin_nontemporal_store(coord_b[3u * (unsigned)batch[i] + c], &out_coord[g]);
    }

    const int tot_l = N * 25;
    for (int g = g0; g < tot_l; g += stride) {
        unsigned ug = (unsigned)g;
        unsigned i = ug / 25u;
        unsigned q = ug - i * 25u;
        f32x4_n v = logits_b4[25u * (unsigned)batch[i] + q];
        __builtin_nontemporal_store(v, &out_logits4[g]);
    }
}

extern "C" void kernel_launch(void* const* d_in, const int* in_sizes, int n_in,
                              void* d_out, int out_size, void* d_ws, size_t ws_size,
                              hipStream_t stream)
{
    const int*   batch = (const int*)d_in[1];
    const float* t_emb = (const float*)d_in[3];
    const float* w1a = (const float*)d_in[4];
    const float* b1a = (const float*)d_in[5];
    const float* w2a = (const float*)d_in[6];
    const float* b2a = (const float*)d_in[7];
    const float* wc1 = (const float*)d_in[8];
    const float* bc1 = (const float*)d_in[9];
    const float* wc2 = (const float*)d_in[10];
    const float* bc2 = (const float*)d_in[11];
    const float* wl1 = (const float*)d_in[12];
    const float* bl1 = (const float*)d_in[13];
    const float* wl2 = (const float*)d_in[14];
    const float* bl2 = (const float*)d_in[15];
    const float* wt  = (const float*)d_in[16];
    const float* bt  = (const float*)d_in[17];

    const int N = in_sizes[1];        // 500000
    const int B = in_sizes[2] / 9;    // 4096

    float* out        = (float*)d_out;
    float* out_coord  = out;                                   // [N,3]
    float* cell_out   = out + (size_t)N * 3;                   // [B,6]
    float* out_logits = out + (size_t)N * 3 + (size_t)B * 6;   // [N,100]

    float* logits_b = (float*)d_ws;                            // B*100 floats
    float* coord_b  = logits_b + (size_t)B * NTYPE;            // B*3 floats

    crystal_kernel<<<B / RPB, THREADS, 0, stream>>>(
        batch, N, t_emb,
        w1a, b1a, w2a, b2a,
        wc1, bc1, wc2, bc2,
        wl1, bl1, wl2, bl2,
        wt, bt,
        coord_b, logits_b, cell_out);

    scatter_kernel<<<2048, 256, 0, stream>>>(
        batch, coord_b, (const f32x4_n*)logits_b,
        out_coord, (f32x4_n*)out_logits, N);
}

// Round 10
// 92.758 us; speedup vs baseline: 1.1855x; 1.1855x over previous
//
#include <hip/hip_runtime.h>

#define HDIM    256
#define HHALF   128
#define NTYPE   100
#define RPB     8      // crystals (rows) per block
#define S       260    // LDS h-row stride in floats
#define THREADS 512
#define PSTRIDE 33     // partials stride: (33*cg+o)%32 = (cg+o)%32 -> 2-way = free
#define REGION  2112   // 64 * 33 floats per K-group partial region

typedef float f32x4_n __attribute__((ext_vector_type(4)));

__device__ __forceinline__ float silu_f(float x) {
    return x / (1.0f + __expf(-x));
}

#define LD4(p) (*(const float4*)(p))
#define FMA4(A, s, v) do { (A).x += (s)*(v).x; (A).y += (s)*(v).y; \
                           (A).z += (s)*(v).z; (A).w += (s)*(v).w; } while (0)

// 8 rows x 4 cols per thread over KT k-rows. Weights double-buffered in
// registers (4 rows in flight). Each W row is read by exactly ONE wave per
// block -> no redundant L1 traffic. h reads are wave-uniform LDS broadcasts.
template<int KT>
__device__ __forceinline__ void gemm_8x4(
    const float* hbase,                 // &buf[kbase]; reads hbase + r*S + k
    const float* __restrict__ W,        // W + kbase*ldw + j0
    const int ldw, float4* acc)
{
    float4 wA0 = LD4(W);           float4 wA1 = LD4(W + ldw);
    float4 wA2 = LD4(W + 2 * ldw); float4 wA3 = LD4(W + 3 * ldw);
#pragma unroll 1
    for (int k4 = 0; k4 < KT - 4; k4 += 4) {
        const float* Wn = W + (size_t)(k4 + 4) * ldw;
        float4 wB0 = LD4(Wn);           float4 wB1 = LD4(Wn + ldw);
        float4 wB2 = LD4(Wn + 2 * ldw); float4 wB3 = LD4(Wn + 3 * ldw);
#pragma unroll
        for (int r = 0; r < 8; ++r) {
            float4 h4 = LD4(hbase + r * S + k4);
            FMA4(acc[r], h4.x, wA0); FMA4(acc[r], h4.y, wA1);
            FMA4(acc[r], h4.z, wA2); FMA4(acc[r], h4.w, wA3);
        }
        wA0 = wB0; wA1 = wB1; wA2 = wB2; wA3 = wB3;
    }
#pragma unroll
    for (int r = 0; r < 8; ++r) {
        float4 h4 = LD4(hbase + r * S + (KT - 4));
        FMA4(acc[r], h4.x, wA0); FMA4(acc[r], h4.y, wA1);
        FMA4(acc[r], h4.z, wA2); FMA4(acc[r], h4.w, wA3);
    }
}

// write 8x4 partials (32 consecutive floats at stride-33 slot) -- conflict-free
__device__ __forceinline__ void part_wr(float* rp, const float4* acc) {
#pragma unroll
    for (int r = 0; r < 8; ++r) {
        rp[r*4+0] = acc[r].x; rp[r*4+1] = acc[r].y;
        rp[r*4+2] = acc[r].z; rp[r*4+3] = acc[r].w;
    }
}

__device__ __forceinline__ void part_add(const float* rbase, int nparts,
                                         int rstride, float4* acc) {
    for (int p = 0; p < nparts; ++p) {
        const float* rp = rbase + (size_t)p * rstride;
#pragma unroll
        for (int r = 0; r < 8; ++r) {
            acc[r].x += rp[r*4+0]; acc[r].y += rp[r*4+1];
            acc[r].z += rp[r*4+2]; acc[r].w += rp[r*4+3];
        }
    }
}

// One block = 8 crystals, 512 threads = 64 col-groups x 8 K-groups (wave=K-group).
__global__ __launch_bounds__(THREADS, 4) void crystal_kernel(
    const int* __restrict__ batch, int N,
    const float* __restrict__ t_emb,
    const float* __restrict__ w1a, const float* __restrict__ b1a,
    const float* __restrict__ w2a, const float* __restrict__ b2a,
    const float* __restrict__ wc1, const float* __restrict__ bc1,
    const float* __restrict__ wc2, const float* __restrict__ bc2,
    const float* __restrict__ wl1, const float* __restrict__ bl1,
    const float* __restrict__ wl2, const float* __restrict__ bl2,
    const float* __restrict__ wt,  const float* __restrict__ bt,
    float* __restrict__ coord_b,   // [B,3]  ws
    float* __restrict__ logits_b,  // [B,100] ws
    float* __restrict__ cell_out)  // d_out + N*3, [B,6]
{
    __shared__ float bufA[RPB * S];      // h0, then h
    __shared__ float bufB[RPB * S];      // h1, then gc(0..127)/gl(128..255)
    __shared__ float red[7 * REGION];    // 57.75 KB cross-K partials
    __shared__ int   lb_s[RPB + 1];
    __shared__ float cnt_s[RPB];

    const int tid = threadIdx.x;
    const int R0  = blockIdx.x * RPB;

    // atom ranges via binary search on sorted batch
    if (tid <= RPB) {
        int v = R0 + tid;
        int lo = 0, hi = N;
        while (lo < hi) { int mid = (lo + hi) >> 1; if (batch[mid] < v) lo = mid + 1; else hi = mid; }
        lb_s[tid] = lo;
    }

    // stage t_emb rows R0..R0+7 (one float4 per thread, coalesced)
    {
        const float4* src = (const float4*)(t_emb + (size_t)R0 * HDIM);
        int r = tid >> 6, kq = tid & 63;
        *(float4*)&bufA[r * S + kq * 4] = src[r * 64 + kq];
    }
    __syncthreads();
    if (tid < RPB) cnt_s[tid] = (float)(lb_s[tid + 1] - lb_s[tid]);

    const int cg  = tid & 63;    // col-group: j0..j0+3
    const int ksg = tid >> 6;    // K-group == wave id (0..7)
    const int j0  = cg * 4;

    float4 acc[8];

    // ---------------- layer 1: h1 = silu(h0 @ w1a + b1a)   bufA -> bufB
    {
#pragma unroll
        for (int r = 0; r < 8; ++r) acc[r] = make_float4(0.f, 0.f, 0.f, 0.f);
        gemm_8x4<32>(&bufA[ksg * 32], w1a + (size_t)(ksg * 32) * HDIM + j0, HDIM, acc);
        if (ksg) part_wr(&red[(ksg - 1) * REGION + cg * PSTRIDE], acc);
        __syncthreads();
        if (!ksg) {
            part_add(&red[cg * PSTRIDE], 7, REGION, acc);
            float4 b4 = LD4(b1a + j0);
#pragma unroll
            for (int r = 0; r < 8; ++r) {
                float4 v;
                v.x = silu_f(acc[r].x + b4.x); v.y = silu_f(acc[r].y + b4.y);
                v.z = silu_f(acc[r].z + b4.z); v.w = silu_f(acc[r].w + b4.w);
                *(float4*)&bufB[r * S + j0] = v;
            }
        }
        __syncthreads();
    }

    // ---------------- layer 2: h = h1 @ w2a + b2a          bufB -> bufA
    {
#pragma unroll
        for (int r = 0; r < 8; ++r) acc[r] = make_float4(0.f, 0.f, 0.f, 0.f);
        gemm_8x4<32>(&bufB[ksg * 32], w2a + (size_t)(ksg * 32) * HDIM + j0, HDIM, acc);
        if (ksg) part_wr(&red[(ksg - 1) * REGION + cg * PSTRIDE], acc);
        __syncthreads();
        if (!ksg) {
            part_add(&red[cg * PSTRIDE], 7, REGION, acc);
            float4 b4 = LD4(b2a + j0);
#pragma unroll
            for (int r = 0; r < 8; ++r) {
                float4 v;
                v.x = acc[r].x + b4.x; v.y = acc[r].y + b4.y;
                v.z = acc[r].z + b4.z; v.w = acc[r].w + b4.w;
                *(float4*)&bufA[r * S + j0] = v;
            }
        }
        __syncthreads();
    }

    // ---------------- heads: coord (tid<256) / cell (tid>=256)   bufA -> bufB
    // K = HDIM = 256: 8 hks-groups x 32 k-rows (R9 bug: was 16 -> half of K)
    {
        const int  t   = tid & 255;
        const bool ic  = (tid >= 256);
        const int  hcg = t & 31;      // 32 col-groups x 4 = 128 cols
        const int  hks = t >> 5;      // K-group 0..7, 32 k-rows each
        const int  hj0 = hcg * 4;
        const float* W  = ic ? wl1 : wc1;
        const float* bb = ic ? bl1 : bc1;
        const int  rbase = (ic ? 7 : 0) * 1056;   // 1056 = 32*33 per region

#pragma unroll
        for (int r = 0; r < 8; ++r) acc[r] = make_float4(0.f, 0.f, 0.f, 0.f);
        gemm_8x4<32>(&bufA[hks * 32], W + (size_t)(hks * 32) * HHALF + hj0, HHALF, acc);
        if (hks) part_wr(&red[rbase + (hks - 1) * 1056 + hcg * PSTRIDE], acc);
        __syncthreads();
        if (!hks) {
            part_add(&red[rbase + hcg * PSTRIDE], 7, 1056, acc);
            float4 b4 = LD4(bb + hj0);
            const int off = ic ? HHALF : 0;
#pragma unroll
            for (int r = 0; r < 8; ++r) {
                // segment_sum == count*h; scale commutes through the dot product
                const float sc = ic ? cnt_s[r] : 1.f;
                float4 v;
                v.x = silu_f(acc[r].x * sc + b4.x); v.y = silu_f(acc[r].y * sc + b4.y);
                v.z = silu_f(acc[r].z * sc + b4.z); v.w = silu_f(acc[r].w * sc + b4.w);
                *(float4*)&bufB[r * S + off + hj0] = v;
            }
        }
        __syncthreads();
    }

    // ---------------- logits (cg<25) + tiny heads (cg>=25)
    {
        if (cg < 25) {
#pragma unroll
            for (int r = 0; r < 8; ++r) acc[r] = make_float4(0.f, 0.f, 0.f, 0.f);
            gemm_8x4<32>(&bufA[ksg * 32], wt + (size_t)(ksg * 32) * NTYPE + j0, NTYPE, acc);
            if (ksg) part_wr(&red[(ksg - 1) * REGION + cg * PSTRIDE], acc);
        } else {
            // 312 spare lanes cover 24 coord + 48 cell outputs (K=128 dots)
            const int idx = ksg * 39 + (cg - 25);
            if (idx < 24) {
                int r = idx / 3, c = idx - 3 * r;
                float a = 0.f;
#pragma unroll 4
                for (int k = 0; k < HHALF; k += 4) {
                    float4 hv = LD4(&bufB[r * S + k]);
                    a += hv.x * wc2[(k + 0) * 3 + c] + hv.y * wc2[(k + 1) * 3 + c]
                       + hv.z * wc2[(k + 2) * 3 + c] + hv.w * wc2[(k + 3) * 3 + c];
                }
                coord_b[(size_t)(R0 + r) * 3 + c] = a + bc2[c];
            } else if (idx < 72) {
                int t2 = idx - 24;
                int r = t2 / 6, c = t2 - 6 * r;
                float a = 0.f;
#pragma unroll 4
                for (int k = 0; k < HHALF; k += 4) {
                    float4 hv = LD4(&bufB[r * S + HHALF + k]);
                    a += hv.x * wl2[(k + 0) * 6 + c] + hv.y * wl2[(k + 1) * 6 + c]
                       + hv.z * wl2[(k + 2) * 6 + c] + hv.w * wl2[(k + 3) * 6 + c];
                }
                cell_out[(size_t)(R0 + r) * 6 + c] = a + bl2[c];
            }
        }
        __syncthreads();
        if (!ksg && cg < 25) {
            part_add(&red[cg * PSTRIDE], 7, REGION, acc);
            float4 b4 = LD4(bt + j0);
#pragma unroll
            for (int r = 0; r < 8; ++r) {
                *(float4*)&logits_b[(size_t)(R0 + r) * NTYPE + j0] =
                    make_float4(acc[r].x + b4.x, acc[r].y + b4.y,
                                acc[r].z + b4.z, acc[r].w + b4.w);
            }
        }
    }
}

// Gather per-crystal tables out to per-atom outputs. HBM-write-bound (~206 MB).
__global__ __launch_bounds__(256) void scatter_kernel(
    const int* __restrict__ batch,
    const float*  __restrict__ coord_b,
    const f32x4_n* __restrict__ logits_b4,  // [B][25] float4
    float*  __restrict__ out_coord,         // [N*3]
    f32x4_n* __restrict__ out_logits4,      // [N*25] float4
    int N)
{
    const int stride = gridDim.x * blockDim.x;
    const int g0 = blockIdx.x * blockDim.x + threadIdx.x;

    const int tot_c = N * 3;
    for (int g = g0; g < tot_c; g += stride) {
        unsigned ug = (unsigned)g;
        unsigned i = ug / 3u;
        unsigned c = ug - i * 3u;
        __builtin_nontemporal_store(coord_b[3u * (unsigned)batch[i] + c], &out_coord[g]);
    }

    const int tot_l = N * 25;
    for (int g = g0; g < tot_l; g += stride) {
        unsigned ug = (unsigned)g;
        unsigned i = ug / 25u;
        unsigned q = ug - i * 25u;
        f32x4_n v = logits_b4[25u * (unsigned)batch[i] + q];
        __builtin_nontemporal_store(v, &out_logits4[g]);
    }
}

extern "C" void kernel_launch(void* const* d_in, const int* in_sizes, int n_in,
                              void* d_out, int out_size, void* d_ws, size_t ws_size,
                              hipStream_t stream)
{
    const int*   batch = (const int*)d_in[1];
    const float* t_emb = (const float*)d_in[3];
    const float* w1a = (const float*)d_in[4];
    const float* b1a = (const float*)d_in[5];
    const float* w2a = (const float*)d_in[6];
    const float* b2a = (const float*)d_in[7];
    const float* wc1 = (const float*)d_in[8];
    const float* bc1 = (const float*)d_in[9];
    const float* wc2 = (const float*)d_in[10];
    const float* bc2 = (const float*)d_in[11];
    const float* wl1 = (const float*)d_in[12];
    const float* bl1 = (const float*)d_in[13];
    const float* wl2 = (const float*)d_in[14];
    const float* bl2 = (const float*)d_in[15];
    const float* wt  = (const float*)d_in[16];
    const float* bt  = (const float*)d_in[17];

    const int N = in_sizes[1];        // 500000
    const int B = in_sizes[2] / 9;    // 4096

    float* out        = (float*)d_out;
    float* out_coord  = out;                                   // [N,3]
    float* cell_out   = out + (size_t)N * 3;                   // [B,6]
    float* out_logits = out + (size_t)N * 3 + (size_t)B * 6;   // [N,100]

    float* logits_b = (float*)d_ws;                            // B*100 floats
    float* coord_b  = logits_b + (size_t)B * NTYPE;            // B*3 floats

    crystal_kernel<<<B / RPB, THREADS, 0, stream>>>(
        batch, N, t_emb,
        w1a, b1a, w2a, b2a,
        wc1, bc1, wc2, bc2,
        wl1, bl1, wl2, bl2,
        wt, bt,
        coord_b, logits_b, cell_out);

    scatter_kernel<<<2048, 256, 0, stream>>>(
        batch, coord_b, (const f32x4_n*)logits_b,
        out_coord, (f32x4_n*)out_logits, N);
}

// Round 11
// 90.957 us; speedup vs baseline: 1.2090x; 1.0198x over previous
//
#include <hip/hip_runtime.h>

#define HDIM    256
#define HHALF   128
#define NTYPE   100
#define RPB     8      // crystals (rows) per block
#define S       260    // LDS h-row stride in floats
#define THREADS 512
#define PSTRIDE 33     // partials stride: (33*cg+o)%32 = (cg+o)%32 -> 2-way = free
#define REGION  2112   // 64 * 33 floats per K-group partial region

typedef float f32x4_n __attribute__((ext_vector_type(4)));

__device__ __forceinline__ float silu_f(float x) {
    return x / (1.0f + __expf(-x));
}

#define LD4(p) (*(const float4*)(p))
#define FMA4(A, s, v) do { (A).x += (s)*(v).x; (A).y += (s)*(v).y; \
                           (A).z += (s)*(v).z; (A).w += (s)*(v).w; } while (0)

// 8 rows x 4 cols per thread over KT k-rows. Weights double-buffered in
// registers. Each W row is read by exactly ONE wave per block (no redundant
// L1 traffic). h reads are wave-uniform LDS broadcasts.
template<int KT>
__device__ __forceinline__ void gemm_8x4(
    const float* hbase,                 // &buf[kbase]; reads hbase + r*S + k
    const float* __restrict__ W,        // W + kbase*ldw + j0
    const int ldw, float4* acc)
{
    float4 wA0 = LD4(W);           float4 wA1 = LD4(W + ldw);
    float4 wA2 = LD4(W + 2 * ldw); float4 wA3 = LD4(W + 3 * ldw);
#pragma unroll 1
    for (int k4 = 0; k4 < KT - 4; k4 += 4) {
        const float* Wn = W + (size_t)(k4 + 4) * ldw;
        float4 wB0 = LD4(Wn);           float4 wB1 = LD4(Wn + ldw);
        float4 wB2 = LD4(Wn + 2 * ldw); float4 wB3 = LD4(Wn + 3 * ldw);
#pragma unroll
        for (int r = 0; r < 8; ++r) {
            float4 h4 = LD4(hbase + r * S + k4);
            FMA4(acc[r], h4.x, wA0); FMA4(acc[r], h4.y, wA1);
            FMA4(acc[r], h4.z, wA2); FMA4(acc[r], h4.w, wA3);
        }
        wA0 = wB0; wA1 = wB1; wA2 = wB2; wA3 = wB3;
    }
#pragma unroll
    for (int r = 0; r < 8; ++r) {
        float4 h4 = LD4(hbase + r * S + (KT - 4));
        FMA4(acc[r], h4.x, wA0); FMA4(acc[r], h4.y, wA1);
        FMA4(acc[r], h4.z, wA2); FMA4(acc[r], h4.w, wA3);
    }
}

__device__ __forceinline__ void part_wr(float* rp, const float4* acc) {
#pragma unroll
    for (int r = 0; r < 8; ++r) {
        rp[r*4+0] = acc[r].x; rp[r*4+1] = acc[r].y;
        rp[r*4+2] = acc[r].z; rp[r*4+3] = acc[r].w;
    }
}

__device__ __forceinline__ void part_add(const float* rbase, int nparts,
                                         int rstride, float4* acc) {
    for (int p = 0; p < nparts; ++p) {
        const float* rp = rbase + (size_t)p * rstride;
#pragma unroll
        for (int r = 0; r < 8; ++r) {
            acc[r].x += rp[r*4+0]; acc[r].y += rp[r*4+1];
            acc[r].z += rp[r*4+2]; acc[r].w += rp[r*4+3];
        }
    }
}

// One block = 8 crystals, 512 threads. Computes MLP + heads AND streams the
// per-atom outputs (atoms contiguous: batch sorted). Waves 0-1 compute the
// head hidden layers WHILE waves 2-7 stream 206 MB of logits (overlap).
__global__ __launch_bounds__(THREADS, 4) void fused_kernel(
    const int* __restrict__ batch, int N,
    const float* __restrict__ t_emb,
    const float* __restrict__ w1a, const float* __restrict__ b1a,
    const float* __restrict__ w2a, const float* __restrict__ b2a,
    const float* __restrict__ wc1, const float* __restrict__ bc1,
    const float* __restrict__ wc2, const float* __restrict__ bc2,
    const float* __restrict__ wl1, const float* __restrict__ bl1,
    const float* __restrict__ wl2, const float* __restrict__ bl2,
    const float* __restrict__ wt,  const float* __restrict__ bt,
    float* __restrict__ out_coord,    // [N,3]
    float* __restrict__ cell_out,     // [B,6]
    f32x4_n* __restrict__ out_logits4)// [N,25] f4
{
    __shared__ float bufA[RPB * S];      // h0, then h
    __shared__ float bufB[RPB * S];      // h1, then gc(0..127)/gl(128..255)
    __shared__ float red[7 * REGION];    // 57.75 KB cross-K partials
    __shared__ float logits_s[RPB * 104];
    __shared__ float coord_s[RPB * 4];
    __shared__ int   lb_s[RPB + 1];
    __shared__ float cnt_s[RPB];

    const int tid = threadIdx.x;
    const int R0  = blockIdx.x * RPB;

    // atom ranges via binary search on sorted batch
    if (tid <= RPB) {
        int v = R0 + tid;
        int lo = 0, hi = N;
        while (lo < hi) { int mid = (lo + hi) >> 1; if (batch[mid] < v) lo = mid + 1; else hi = mid; }
        lb_s[tid] = lo;
    }

    // stage t_emb rows R0..R0+7 (one float4 per thread, coalesced)
    {
        const float4* src = (const float4*)(t_emb + (size_t)R0 * HDIM);
        int r = tid >> 6, kq = tid & 63;
        *(float4*)&bufA[r * S + kq * 4] = src[r * 64 + kq];
    }
    __syncthreads();
    if (tid < RPB) cnt_s[tid] = (float)(lb_s[tid + 1] - lb_s[tid]);

    const int cg  = tid & 63;    // col-group: j0..j0+3
    const int ksg = tid >> 6;    // K-group == wave id (0..7)
    const int j0  = cg * 4;

    float4 acc[8];

    // ---------------- layer 1: h1 = silu(h0 @ w1a + b1a)   bufA -> bufB
    {
#pragma unroll
        for (int r = 0; r < 8; ++r) acc[r] = make_float4(0.f, 0.f, 0.f, 0.f);
        gemm_8x4<32>(&bufA[ksg * 32], w1a + (size_t)(ksg * 32) * HDIM + j0, HDIM, acc);
        if (ksg) part_wr(&red[(ksg - 1) * REGION + cg * PSTRIDE], acc);
        __syncthreads();
        if (!ksg) {
            part_add(&red[cg * PSTRIDE], 7, REGION, acc);
            float4 b4 = LD4(b1a + j0);
#pragma unroll
            for (int r = 0; r < 8; ++r) {
                float4 v;
                v.x = silu_f(acc[r].x + b4.x); v.y = silu_f(acc[r].y + b4.y);
                v.z = silu_f(acc[r].z + b4.z); v.w = silu_f(acc[r].w + b4.w);
                *(float4*)&bufB[r * S + j0] = v;
            }
        }
        __syncthreads();
    }

    // ---------------- layer 2: h = h1 @ w2a + b2a          bufB -> bufA
    {
#pragma unroll
        for (int r = 0; r < 8; ++r) acc[r] = make_float4(0.f, 0.f, 0.f, 0.f);
        gemm_8x4<32>(&bufB[ksg * 32], w2a + (size_t)(ksg * 32) * HDIM + j0, HDIM, acc);
        if (ksg) part_wr(&red[(ksg - 1) * REGION + cg * PSTRIDE], acc);
        __syncthreads();
        if (!ksg) {
            part_add(&red[cg * PSTRIDE], 7, REGION, acc);
            float4 b4 = LD4(b2a + j0);
#pragma unroll
            for (int r = 0; r < 8; ++r) {
                float4 v;
                v.x = acc[r].x + b4.x; v.y = acc[r].y + b4.y;
                v.z = acc[r].z + b4.z; v.w = acc[r].w + b4.w;
                *(float4*)&bufA[r * S + j0] = v;
            }
        }
        __syncthreads();
    }

    // ---------------- logits: h @ wt + bt -> logits_s (LDS)
    {
        if (cg < 25) {
#pragma unroll
            for (int r = 0; r < 8; ++r) acc[r] = make_float4(0.f, 0.f, 0.f, 0.f);
            gemm_8x4<32>(&bufA[ksg * 32], wt + (size_t)(ksg * 32) * NTYPE + j0, NTYPE, acc);
            if (ksg) part_wr(&red[(ksg - 1) * REGION + cg * PSTRIDE], acc);
        }
        __syncthreads();
        if (!ksg && cg < 25) {
            part_add(&red[cg * PSTRIDE], 7, REGION, acc);
            float4 b4 = LD4(bt + j0);
#pragma unroll
            for (int r = 0; r < 8; ++r) {
                *(float4*)&logits_s[r * 104 + j0] =
                    make_float4(acc[r].x + b4.x, acc[r].y + b4.y,
                                acc[r].z + b4.z, acc[r].w + b4.w);
            }
        }
        __syncthreads();
    }

    // -------- OVERLAP: waves 0-1 head hidden GEMMs || waves 2-7 logits stream
    if (tid < 128) {
        // 128 threads = 32 hcg x 2 hks x 2 ic (wave0 = coord, wave1 = cell)
        const int  hcg = tid & 31;
        const int  hks = (tid >> 5) & 1;   // K-half: 128 rows each
        const bool ic  = (tid >= 64);
        const int  hj0 = hcg * 4;
        const float* W  = ic ? wl1 : wc1;
        const float* bb = ic ? bl1 : bc1;
        const int  rbase = ic ? 1056 : 0;  // 1056 = 32*33 floats per region

        float4 hacc[8];
#pragma unroll
        for (int r = 0; r < 8; ++r) hacc[r] = make_float4(0.f, 0.f, 0.f, 0.f);
        gemm_8x4<128>(&bufA[hks * 128], W + (size_t)(hks * 128) * HHALF + hj0,
                      HHALF, hacc);
        if (hks) part_wr(&red[rbase + hcg * PSTRIDE], hacc);
        __syncthreads();   // barrier A (store waves arrive after issuing stores)
        if (!hks) {
            part_add(&red[rbase + hcg * PSTRIDE], 1, 0, hacc);
            float4 b4 = LD4(bb + hj0);
            const int off = ic ? HHALF : 0;
#pragma unroll
            for (int r = 0; r < 8; ++r) {
                // segment_sum == count*h; scale commutes through the dot
                const float sc = ic ? cnt_s[r] : 1.f;
                float4 v;
                v.x = silu_f(hacc[r].x * sc + b4.x); v.y = silu_f(hacc[r].y * sc + b4.y);
                v.z = silu_f(hacc[r].z * sc + b4.z); v.w = silu_f(hacc[r].w * sc + b4.w);
                *(float4*)&bufB[r * S + off + hj0] = v;
            }
        }
    } else {
        // 384 threads stream per-atom logits (coalesced nontemporal f4 stores)
        const int st = tid - 128;
        const f32x4_n* ls4 = (const f32x4_n*)logits_s;   // row stride 26 f4
#pragma unroll 1
        for (int r = 0; r < RPB; ++r) {
            const int base = lb_s[r];
            const int tot  = (lb_s[r + 1] - base) * 25;
            const f32x4_n* lrow = ls4 + r * 26;
            for (int t = st; t < tot; t += 384) {
                unsigned a = (unsigned)t / 25u;
                unsigned q = (unsigned)t - a * 25u;
                f32x4_n v = lrow[q];
                __builtin_nontemporal_store(v, &out_logits4[(size_t)(base + a) * 25 + q]);
            }
        }
        __syncthreads();   // barrier A
    }
    __syncthreads();       // barrier B: bufB head outputs visible

    // ---------------- tiny heads: coord [8x3] -> coord_s, cell [8x6] -> global
    if (tid < 24) {
        int r = tid / 3, c = tid - 3 * r;
        float a = 0.f;
#pragma unroll 4
        for (int k = 0; k < HHALF; k += 4) {
            float4 hv = LD4(&bufB[r * S + k]);
            a += hv.x * wc2[(k + 0) * 3 + c] + hv.y * wc2[(k + 1) * 3 + c]
               + hv.z * wc2[(k + 2) * 3 + c] + hv.w * wc2[(k + 3) * 3 + c];
        }
        coord_s[r * 4 + c] = a + bc2[c];
    } else if (tid < 72) {
        int t2 = tid - 24;
        int r = t2 / 6, c = t2 - 6 * r;
        float a = 0.f;
#pragma unroll 4
        for (int k = 0; k < HHALF; k += 4) {
            float4 hv = LD4(&bufB[r * S + HHALF + k]);
            a += hv.x * wl2[(k + 0) * 6 + c] + hv.y * wl2[(k + 1) * 6 + c]
               + hv.z * wl2[(k + 2) * 6 + c] + hv.w * wl2[(k + 3) * 6 + c];
        }
        cell_out[(size_t)(R0 + r) * 6 + c] = a + bl2[c];
    }
    __syncthreads();

    // ---------------- per-atom coord stream (6 MB, coalesced)
#pragma unroll 1
    for (int r = 0; r < RPB; ++r) {
        const int base = lb_s[r];
        const int tot3 = (lb_s[r + 1] - base) * 3;
        const float c0 = coord_s[r * 4 + 0];
        const float c1 = coord_s[r * 4 + 1];
        const float c2 = coord_s[r * 4 + 2];
        float* oc = out_coord + (size_t)base * 3;
        for (int t = tid; t < tot3; t += THREADS) {
            unsigned a = (unsigned)t / 3u;
            unsigned c = (unsigned)t - a * 3u;
            float v = (c == 0) ? c0 : (c == 1) ? c1 : c2;
            __builtin_nontemporal_store(v, &oc[t]);
        }
    }
}

extern "C" void kernel_launch(void* const* d_in, const int* in_sizes, int n_in,
                              void* d_out, int out_size, void* d_ws, size_t ws_size,
                              hipStream_t stream)
{
    const int*   batch = (const int*)d_in[1];
    const float* t_emb = (const float*)d_in[3];
    const float* w1a = (const float*)d_in[4];
    const float* b1a = (const float*)d_in[5];
    const float* w2a = (const float*)d_in[6];
    const float* b2a = (const float*)d_in[7];
    const float* wc1 = (const float*)d_in[8];
    const float* bc1 = (const float*)d_in[9];
    const float* wc2 = (const float*)d_in[10];
    const float* bc2 = (const float*)d_in[11];
    const float* wl1 = (const float*)d_in[12];
    const float* bl1 = (const float*)d_in[13];
    const float* wl2 = (const float*)d_in[14];
    const float* bl2 = (const float*)d_in[15];
    const float* wt  = (const float*)d_in[16];
    const float* bt  = (const float*)d_in[17];

    const int N = in_sizes[1];        // 500000
    const int B = in_sizes[2] / 9;    // 4096

    float* out        = (float*)d_out;
    float* out_coord  = out;                                   // [N,3]
    float* cell_out   = out + (size_t)N * 3;                   // [B,6]
    float* out_logits = out + (size_t)N * 3 + (size_t)B * 6;   // [N,100]

    fused_kernel<<<B / RPB, THREADS, 0, stream>>>(
        batch, N, t_emb,
        w1a, b1a, w2a, b2a,
        wc1, bc1, wc2, bc2,
        wl1, bl1, wl2, bl2,
        wt, bt,
        out_coord, cell_out, (f32x4_n*)out_logits);
}